// Round 1
// baseline (546.403 us; speedup 1.0000x reference)
//
#include <hip/hip_runtime.h>

// AGRU cell: B=2048, T=200, D=U=64, all fp32.
// One wave handles 2 batch rows across all T; lane = u (output unit).
// Weights staged once into LDS as [matrix][j][u] (64KB exactly, conflict-free
// stride-1 lane access, pure immediate ds offsets). h[j]/x[j] broadcasts via
// v_readlane (VALU). No barriers inside the time loop.

constexpr int T_STEPS = 200;
constexpr int UDIM = 64;

__device__ __forceinline__ float lane_bcast(float v, int lane) {
    return __builtin_bit_cast(float, __builtin_amdgcn_readlane(__builtin_bit_cast(int, v), lane));
}

__device__ __forceinline__ float fast_sigmoid(float z) {
    // 1/(1+e^-z); e^-z -> inf for very negative z gives 0 correctly.
    return __builtin_amdgcn_rcpf(1.0f + __expf(-z));
}

__device__ __forceinline__ float fast_tanh(float z) {
    // 1 - 2/(e^{2z}+1); saturates correctly to +/-1 on overflow/underflow.
    return 1.0f - 2.0f * __builtin_amdgcn_rcpf(__expf(2.0f * z) + 1.0f);
}

__global__ __launch_bounds__(256) void agru_kernel(
    const float* __restrict__ x,      // [B,T,64]
    const float* __restrict__ att,    // [B,T,1]
    const float* __restrict__ h0,     // [B,64]
    const float* __restrict__ w_ir,   // [64,64]
    const float* __restrict__ w_hr,   // [64,64]
    const float* __restrict__ b_ir,   // [64]
    const float* __restrict__ b_hr,   // [64]
    const float* __restrict__ w_ih,   // [64,64]
    const float* __restrict__ w_hh,   // [64,64]
    const float* __restrict__ b_ih,   // [64]
    const float* __restrict__ b_hh,   // [64]
    float* __restrict__ out)          // [B,T,64]
{
    // LDS: 4 matrices * 64*64 fp32 = 65536 B exactly.
    // Layout per matrix: [j][u]  (row j contiguous in u -> lane-stride-1 reads)
    __shared__ float lds[4 * UDIM * UDIM];

    const int tid = threadIdx.x;
    #pragma unroll
    for (int i = 0; i < 16; ++i) {
        int e = tid + 256 * i;
        lds[e]             = w_ir[e];
        lds[4096 + e]      = w_ih[e];
        lds[8192 + e]      = w_hr[e];
        lds[12288 + e]     = w_hh[e];
    }
    __syncthreads();

    const int wave = tid >> 6;           // 0..3
    const int u    = tid & 63;           // lane = output unit
    const int r0   = blockIdx.x * 8 + wave * 2;
    const int r1   = r0 + 1;

    float h_0 = h0[r0 * UDIM + u];
    float h_1 = h0[r1 * UDIM + u];

    const float bR = b_ir[u] + b_hr[u];
    const float bH = b_ih[u];
    const float bG = b_hh[u];

    const float* xp0 = x   + (long)r0 * T_STEPS * UDIM + u;
    const float* xp1 = x   + (long)r1 * T_STEPS * UDIM + u;
    const float* ap0 = att + (long)r0 * T_STEPS;
    const float* ap1 = att + (long)r1 * T_STEPS;
    float*       op0 = out + (long)r0 * T_STEPS * UDIM + u;
    float*       op1 = out + (long)r1 * T_STEPS * UDIM + u;

    // prefetch t=0
    float xv0 = xp0[0];
    float xv1 = xp1[0];
    float a0  = ap0[0];
    float a1  = ap1[0];

    for (int t = 0; t < T_STEPS; ++t) {
        // prefetch t+1 (clamped; harmless re-read on last step)
        const int tn = (t + 1 < T_STEPS) ? (t + 1) : t;
        float nxv0 = xp0[(long)tn * UDIM];
        float nxv1 = xp1[(long)tn * UDIM];
        float na0  = ap0[tn];
        float na1  = ap1[tn];

        float accR0 = bR, accR1 = bR;   // pre_r + h@w_hr
        float accH0 = bH, accH1 = bH;   // pre_h
        float accG0 = bG, accG1 = bG;   // h@w_hh + b_hh

        #pragma unroll
        for (int j = 0; j < 64; ++j) {
            const float wir = lds[j * 64 + u];
            const float wih = lds[4096  + j * 64 + u];
            const float whr = lds[8192  + j * 64 + u];
            const float whh = lds[12288 + j * 64 + u];

            const float xj0 = lane_bcast(xv0, j);
            const float xj1 = lane_bcast(xv1, j);
            const float hj0 = lane_bcast(h_0, j);
            const float hj1 = lane_bcast(h_1, j);

            accR0 = fmaf(xj0, wir, accR0);
            accR0 = fmaf(hj0, whr, accR0);
            accH0 = fmaf(xj0, wih, accH0);
            accG0 = fmaf(hj0, whh, accG0);

            accR1 = fmaf(xj1, wir, accR1);
            accR1 = fmaf(hj1, whr, accR1);
            accH1 = fmaf(xj1, wih, accH1);
            accG1 = fmaf(hj1, whh, accG1);
        }

        const float r0g = fast_sigmoid(accR0);
        const float r1g = fast_sigmoid(accR1);
        const float hc0 = fast_tanh(fmaf(r0g, accG0, accH0));
        const float hc1 = fast_tanh(fmaf(r1g, accG1, accH1));

        h_0 = fmaf(a0, hc0 - h_0, h_0);   // (1-a)h + a*hc
        h_1 = fmaf(a1, hc1 - h_1, h_1);

        op0[(long)t * UDIM] = h_0;
        op1[(long)t * UDIM] = h_1;

        xv0 = nxv0; xv1 = nxv1; a0 = na0; a1 = na1;
    }
}

extern "C" void kernel_launch(void* const* d_in, const int* in_sizes, int n_in,
                              void* d_out, int out_size, void* d_ws, size_t ws_size,
                              hipStream_t stream) {
    (void)in_sizes; (void)n_in; (void)d_ws; (void)ws_size; (void)out_size;

    const float* x    = (const float*)d_in[0];
    const float* att  = (const float*)d_in[1];
    const float* h0   = (const float*)d_in[2];
    const float* w_ir = (const float*)d_in[3];
    const float* w_hr = (const float*)d_in[4];
    const float* b_ir = (const float*)d_in[5];
    const float* b_hr = (const float*)d_in[6];
    const float* w_ih = (const float*)d_in[7];
    const float* w_hh = (const float*)d_in[8];
    const float* b_ih = (const float*)d_in[9];
    const float* b_hh = (const float*)d_in[10];

    // 2048 rows / (2 rows per wave * 4 waves per block) = 256 blocks
    agru_kernel<<<dim3(256), dim3(256), 0, stream>>>(
        x, att, h0, w_ir, w_hr, b_ir, b_hr, w_ih, w_hh, b_ih, b_hh,
        (float*)d_out);
}

// Round 2
// 407.259 us; speedup vs baseline: 1.3417x; 1.3417x over previous
//
#include <hip/hip_runtime.h>

// AGRU: B=2048, T=200, D=U=64, fp32.
// Split design:
//  K1 proj_kernel: pre_r/pre_h = x @ w_ir/w_ih + biases for all (b,t).
//     Weights in 128 VGPRs/lane; x-row via wave-uniform scalar loads.
//  K2 rec_kernel: serial T-loop, 1 batch row per wave, hidden weights in
//     128 VGPRs/lane (NO LDS -> no per-step LDS bandwidth, occupancy 2/SIMD),
//     h[j] broadcast via v_readlane.
// Scratch: pre as float2[B*T*64] = 210 MB in d_ws; falls back to fused
// round-1 kernel if ws_size is too small.

constexpr int BATCH = 2048;
constexpr int T_STEPS = 200;
constexpr int UDIM = 64;

__device__ __forceinline__ float lane_bcast(float v, int lane) {
    return __builtin_bit_cast(float, __builtin_amdgcn_readlane(__builtin_bit_cast(int, v), lane));
}

__device__ __forceinline__ float fast_sigmoid(float z) {
    return __builtin_amdgcn_rcpf(1.0f + __expf(-z));
}

__device__ __forceinline__ float fast_tanh(float z) {
    return 1.0f - 2.0f * __builtin_amdgcn_rcpf(__expf(2.0f * z) + 1.0f);
}

// ---------------- Kernel 1: input projections ----------------
__global__ __launch_bounds__(256) void proj_kernel(
    const float* __restrict__ x,     // [B*T,64]
    const float* __restrict__ w_ir,  // [64,64]
    const float* __restrict__ w_ih,  // [64,64]
    const float* __restrict__ b_ir,
    const float* __restrict__ b_hr,
    const float* __restrict__ b_ih,
    float2* __restrict__ pre)        // [B*T,64] of {pre_r, pre_h}
{
    const int u = threadIdx.x & 63;

    float wir[UDIM], wih[UDIM];
    #pragma unroll
    for (int j = 0; j < UDIM; ++j) {
        wir[j] = w_ir[j * UDIM + u];   // coalesced: lanes read contiguous 256B
        wih[j] = w_ih[j * UDIM + u];
    }
    const float br = b_ir[u] + b_hr[u];
    const float bh = b_ih[u];

    const int nwaves = (gridDim.x * blockDim.x) >> 6;
    int wid = (int)((blockIdx.x * blockDim.x + threadIdx.x) >> 6);
    wid = __builtin_amdgcn_readfirstlane(wid);   // force wave-uniform

    const int rows = BATCH * T_STEPS;
    for (int row = wid; row < rows; row += nwaves) {
        const float* xr = x + (long)row * UDIM;  // uniform base -> s_load
        float ar0 = br, ar1 = 0.0f, ah0 = bh, ah1 = 0.0f;
        #pragma unroll
        for (int j = 0; j < UDIM; j += 2) {
            const float xj0 = xr[j];
            const float xj1 = xr[j + 1];
            ar0 = fmaf(xj0, wir[j],     ar0);
            ah0 = fmaf(xj0, wih[j],     ah0);
            ar1 = fmaf(xj1, wir[j + 1], ar1);
            ah1 = fmaf(xj1, wih[j + 1], ah1);
        }
        float2 o; o.x = ar0 + ar1; o.y = ah0 + ah1;
        pre[(long)row * UDIM + u] = o;           // one dwordx2 store
    }
}

// ---------------- Kernel 2: recurrence ----------------
__global__ __launch_bounds__(256) void rec_kernel(
    const float2* __restrict__ pre,  // [B*T,64] {pre_r, pre_h}
    const float* __restrict__ att,   // [B,T]
    const float* __restrict__ h0,    // [B,64]
    const float* __restrict__ w_hr,  // [64,64]
    const float* __restrict__ w_hh,  // [64,64]
    const float* __restrict__ b_hh,  // [64]
    float* __restrict__ out)         // [B,T,64]
{
    const int u = threadIdx.x & 63;
    int row = (int)((blockIdx.x * blockDim.x + threadIdx.x) >> 6);  // 0..2047
    row = __builtin_amdgcn_readfirstlane(row);

    float whr[UDIM], whh[UDIM];
    #pragma unroll
    for (int j = 0; j < UDIM; ++j) {
        whr[j] = w_hr[j * UDIM + u];
        whh[j] = w_hh[j * UDIM + u];
    }
    const float bg = b_hh[u];

    float h = h0[(long)row * UDIM + u];

    const float2* pp = pre + (long)row * T_STEPS * UDIM + u;
    const float*  ap = att + (long)row * T_STEPS;         // uniform -> s_load
    float*        op = out + (long)row * T_STEPS * UDIM + u;

    float2 pv = pp[0];
    float  av = ap[0];

    for (int t = 0; t < T_STEPS; ++t) {
        const int tn = (t + 1 < T_STEPS) ? (t + 1) : t;
        float2 npv = pp[(long)tn * UDIM];
        float  nav = ap[tn];

        float aR0 = 0.f, aR1 = 0.f, aG0 = 0.f, aG1 = 0.f;
        #pragma unroll
        for (int j = 0; j < UDIM; j += 2) {
            const float hj0 = lane_bcast(h, j);
            const float hj1 = lane_bcast(h, j + 1);
            aR0 = fmaf(hj0, whr[j],     aR0);
            aG0 = fmaf(hj0, whh[j],     aG0);
            aR1 = fmaf(hj1, whr[j + 1], aR1);
            aG1 = fmaf(hj1, whh[j + 1], aG1);
        }

        const float r  = fast_sigmoid(pv.x + aR0 + aR1);
        const float hc = fast_tanh(fmaf(r, aG0 + aG1 + bg, pv.y));
        h = fmaf(av, hc - h, h);        // (1-a)h + a*hc

        op[(long)t * UDIM] = h;

        pv = npv; av = nav;
    }
}

// ---------------- Fallback: round-1 fused kernel ----------------
__global__ __launch_bounds__(256) void agru_fused_kernel(
    const float* __restrict__ x, const float* __restrict__ att,
    const float* __restrict__ h0,
    const float* __restrict__ w_ir, const float* __restrict__ w_hr,
    const float* __restrict__ b_ir, const float* __restrict__ b_hr,
    const float* __restrict__ w_ih, const float* __restrict__ w_hh,
    const float* __restrict__ b_ih, const float* __restrict__ b_hh,
    float* __restrict__ out)
{
    __shared__ float lds[4 * UDIM * UDIM];
    const int tid = threadIdx.x;
    #pragma unroll
    for (int i = 0; i < 16; ++i) {
        int e = tid + 256 * i;
        lds[e] = w_ir[e]; lds[4096 + e] = w_ih[e];
        lds[8192 + e] = w_hr[e]; lds[12288 + e] = w_hh[e];
    }
    __syncthreads();

    const int wave = tid >> 6;
    const int u = tid & 63;
    const int r0 = blockIdx.x * 8 + wave * 2;
    const int r1 = r0 + 1;

    float h_0 = h0[r0 * UDIM + u];
    float h_1 = h0[r1 * UDIM + u];
    const float bR = b_ir[u] + b_hr[u];
    const float bH = b_ih[u];
    const float bG = b_hh[u];

    const float* xp0 = x + (long)r0 * T_STEPS * UDIM + u;
    const float* xp1 = x + (long)r1 * T_STEPS * UDIM + u;
    const float* ap0 = att + (long)r0 * T_STEPS;
    const float* ap1 = att + (long)r1 * T_STEPS;
    float* op0 = out + (long)r0 * T_STEPS * UDIM + u;
    float* op1 = out + (long)r1 * T_STEPS * UDIM + u;

    float xv0 = xp0[0], xv1 = xp1[0], a0 = ap0[0], a1 = ap1[0];

    for (int t = 0; t < T_STEPS; ++t) {
        const int tn = (t + 1 < T_STEPS) ? (t + 1) : t;
        float nxv0 = xp0[(long)tn * UDIM], nxv1 = xp1[(long)tn * UDIM];
        float na0 = ap0[tn], na1 = ap1[tn];

        float accR0 = bR, accR1 = bR, accH0 = bH, accH1 = bH, accG0 = bG, accG1 = bG;
        #pragma unroll
        for (int j = 0; j < 64; ++j) {
            const float wir = lds[j * 64 + u];
            const float wih = lds[4096 + j * 64 + u];
            const float whr = lds[8192 + j * 64 + u];
            const float whh = lds[12288 + j * 64 + u];
            const float xj0 = lane_bcast(xv0, j);
            const float xj1 = lane_bcast(xv1, j);
            const float hj0 = lane_bcast(h_0, j);
            const float hj1 = lane_bcast(h_1, j);
            accR0 = fmaf(xj0, wir, accR0); accR0 = fmaf(hj0, whr, accR0);
            accH0 = fmaf(xj0, wih, accH0); accG0 = fmaf(hj0, whh, accG0);
            accR1 = fmaf(xj1, wir, accR1); accR1 = fmaf(hj1, whr, accR1);
            accH1 = fmaf(xj1, wih, accH1); accG1 = fmaf(hj1, whh, accG1);
        }
        const float r0g = fast_sigmoid(accR0);
        const float r1g = fast_sigmoid(accR1);
        const float hc0 = fast_tanh(fmaf(r0g, accG0, accH0));
        const float hc1 = fast_tanh(fmaf(r1g, accG1, accH1));
        h_0 = fmaf(a0, hc0 - h_0, h_0);
        h_1 = fmaf(a1, hc1 - h_1, h_1);
        op0[(long)t * UDIM] = h_0;
        op1[(long)t * UDIM] = h_1;
        xv0 = nxv0; xv1 = nxv1; a0 = na0; a1 = na1;
    }
}

extern "C" void kernel_launch(void* const* d_in, const int* in_sizes, int n_in,
                              void* d_out, int out_size, void* d_ws, size_t ws_size,
                              hipStream_t stream) {
    (void)in_sizes; (void)n_in; (void)out_size;

    const float* x    = (const float*)d_in[0];
    const float* att  = (const float*)d_in[1];
    const float* h0   = (const float*)d_in[2];
    const float* w_ir = (const float*)d_in[3];
    const float* w_hr = (const float*)d_in[4];
    const float* b_ir = (const float*)d_in[5];
    const float* b_hr = (const float*)d_in[6];
    const float* w_ih = (const float*)d_in[7];
    const float* w_hh = (const float*)d_in[8];
    const float* b_ih = (const float*)d_in[9];
    const float* b_hh = (const float*)d_in[10];
    float* out = (float*)d_out;

    const size_t pre_bytes = (size_t)BATCH * T_STEPS * UDIM * sizeof(float2); // 210 MB

    if (ws_size >= pre_bytes) {
        float2* pre = (float2*)d_ws;
        // K1: 768 blocks x 256 thr = 3072 waves, grid-stride over 409600 rows
        proj_kernel<<<dim3(768), dim3(256), 0, stream>>>(
            x, w_ir, w_ih, b_ir, b_hr, b_ih, pre);
        // K2: 2048 waves = 512 blocks, 1 batch row per wave
        rec_kernel<<<dim3(512), dim3(256), 0, stream>>>(
            pre, att, h0, w_hr, w_hh, b_hh, out);
    } else {
        agru_fused_kernel<<<dim3(256), dim3(256), 0, stream>>>(
            x, att, h0, w_ir, w_hr, b_ir, b_hr, w_ih, w_hh, b_ih, b_hh, out);
    }
}

// Round 3
// 291.745 us; speedup vs baseline: 1.8729x; 1.3959x over previous
//
#include <hip/hip_runtime.h>

// AGRU: B=2048, T=200, D=U=64, fp32. Split design v2.
//  K1 proj: pre_{r,h} = x @ {w_ir,w_ih} + biases. Weights packed float2 in
//     128 VGPRs/lane; x via coalesced vector loads + v_readlane broadcast;
//     explicit 4-row-group prefetch (next group's loads issue before current
//     group's compute -> ~1100cy compute covers ~900cy HBM latency).
//  K2 rec: 1 batch row/wave, hidden weights packed float2 in 128 VGPRs,
//     3-step-deep prefetch of pre/att (shift registers, static indexing).
// float2-paired fmaf everywhere to invite v_pk_fma_f32 (VOP3P) formation.

constexpr int BATCH = 2048;
constexpr int T_STEPS = 200;
constexpr int UDIM = 64;

__device__ __forceinline__ float lane_bcast(float v, int lane) {
    return __builtin_bit_cast(float, __builtin_amdgcn_readlane(__builtin_bit_cast(int, v), lane));
}

__device__ __forceinline__ float fast_sigmoid(float z) {
    return __builtin_amdgcn_rcpf(1.0f + __expf(-z));
}

__device__ __forceinline__ float fast_tanh(float z) {
    return 1.0f - 2.0f * __builtin_amdgcn_rcpf(__expf(2.0f * z) + 1.0f);
}

// ---------------- Kernel 1: input projections ----------------
// grid: 1024 blocks x 256 = 4096 waves; 409600 rows = 4096 waves * 25 groups * 4 rows.
__global__ __launch_bounds__(256, 3) void proj_kernel(
    const float* __restrict__ x,     // [B*T,64]
    const float* __restrict__ w_ir,  // [64,64]
    const float* __restrict__ w_ih,  // [64,64]
    const float* __restrict__ b_ir,
    const float* __restrict__ b_hr,
    const float* __restrict__ b_ih,
    float2* __restrict__ pre)        // [B*T,64] of {pre_r, pre_h}
{
    const int u = threadIdx.x & 63;

    float2 w2[UDIM];
    #pragma unroll
    for (int j = 0; j < UDIM; ++j) {
        w2[j].x = w_ir[j * UDIM + u];   // coalesced 256B row reads
        w2[j].y = w_ih[j * UDIM + u];
    }
    const float br = b_ir[u] + b_hr[u];
    const float bh = b_ih[u];

    const int nwaves = (int)((gridDim.x * blockDim.x) >> 6);       // 4096
    const int wid = (int)((blockIdx.x * blockDim.x + threadIdx.x) >> 6);

    const int ngroups = (BATCH * T_STEPS) / 4;                      // 102400
    const float* xp = x + u;

    // peel: load group `wid`
    long r = (long)wid * 4;
    float xa = xp[(r + 0) * UDIM];
    float xb = xp[(r + 1) * UDIM];
    float xc = xp[(r + 2) * UDIM];
    float xd = xp[(r + 3) * UDIM];

    for (int g = wid; g < ngroups; g += nwaves) {
        // prefetch next group (clamped to a valid address; unused on last iter)
        const int gn = (g + nwaves < ngroups) ? (g + nwaves) : g;
        const long rn = (long)gn * 4;
        float na = xp[(rn + 0) * UDIM];
        float nb = xp[(rn + 1) * UDIM];
        float nc = xp[(rn + 2) * UDIM];
        float nd = xp[(rn + 3) * UDIM];

        const long rr = (long)g * 4;
        float2* po = pre + rr * UDIM + u;

        // ---- row 0..3, each: readlane broadcast + paired fmaf ----
        #pragma unroll
        for (int k = 0; k < 4; ++k) {
            const float xv = (k == 0) ? xa : (k == 1) ? xb : (k == 2) ? xc : xd;
            float2 accA; accA.x = br;  accA.y = bh;
            float2 accB; accB.x = 0.f; accB.y = 0.f;
            #pragma unroll
            for (int j = 0; j < UDIM; j += 2) {
                const float s0 = lane_bcast(xv, j);
                const float s1 = lane_bcast(xv, j + 1);
                accA.x = fmaf(s0, w2[j].x,     accA.x);
                accA.y = fmaf(s0, w2[j].y,     accA.y);
                accB.x = fmaf(s1, w2[j + 1].x, accB.x);
                accB.y = fmaf(s1, w2[j + 1].y, accB.y);
            }
            float2 o; o.x = accA.x + accB.x; o.y = accA.y + accB.y;
            po[(long)k * UDIM] = o;     // global_store_dwordx2, 512B/row coalesced
        }

        xa = na; xb = nb; xc = nc; xd = nd;
    }
}

// ---------------- Kernel 2: recurrence ----------------
// 512 blocks x 256 = 2048 waves, 1 batch row per wave.
__global__ __launch_bounds__(256, 2) void rec_kernel(
    const float2* __restrict__ pre,  // [B*T,64] {pre_r, pre_h}
    const float* __restrict__ att,   // [B,T]
    const float* __restrict__ h0,    // [B,64]
    const float* __restrict__ w_hr,  // [64,64]
    const float* __restrict__ w_hh,  // [64,64]
    const float* __restrict__ b_hh,  // [64]
    float* __restrict__ out)         // [B,T,64]
{
    const int u = threadIdx.x & 63;
    const int row = (int)((blockIdx.x * blockDim.x + threadIdx.x) >> 6); // 0..2047

    float2 w2[UDIM];
    #pragma unroll
    for (int j = 0; j < UDIM; ++j) {
        w2[j].x = w_hr[j * UDIM + u];
        w2[j].y = w_hh[j * UDIM + u];
    }
    const float bg = b_hh[u];

    float h = h0[(long)row * UDIM + u];

    const float2* pp = pre + (long)row * T_STEPS * UDIM + u;
    const float*  ap = att + (long)row * T_STEPS;
    float*        op = out + (long)row * T_STEPS * UDIM + u;

    // 3-deep prefetch pipeline (static shift registers)
    float2 pv0 = pp[0 * UDIM];
    float2 pv1 = pp[1 * UDIM];
    float2 pv2 = pp[2 * UDIM];
    float  av0 = ap[0];
    float  av1 = ap[1];
    float  av2 = ap[2];

    for (int t = 0; t < T_STEPS; ++t) {
        const int tf = (t + 3 < T_STEPS) ? (t + 3) : (T_STEPS - 1);
        float2 pvn = pp[(long)tf * UDIM];
        float  avn = ap[tf];

        float2 accA; accA.x = 0.f; accA.y = 0.f;   // {h@w_hr, h@w_hh}
        float2 accB; accB.x = 0.f; accB.y = 0.f;
        #pragma unroll
        for (int j = 0; j < UDIM; j += 2) {
            const float s0 = lane_bcast(h, j);
            const float s1 = lane_bcast(h, j + 1);
            accA.x = fmaf(s0, w2[j].x,     accA.x);
            accA.y = fmaf(s0, w2[j].y,     accA.y);
            accB.x = fmaf(s1, w2[j + 1].x, accB.x);
            accB.y = fmaf(s1, w2[j + 1].y, accB.y);
        }

        const float r  = fast_sigmoid(pv0.x + accA.x + accB.x);
        const float hc = fast_tanh(fmaf(r, accA.y + accB.y + bg, pv0.y));
        h = fmaf(av0, hc - h, h);                  // (1-a)h + a*hc

        op[(long)t * UDIM] = h;

        pv0 = pv1; pv1 = pv2; pv2 = pvn;
        av0 = av1; av1 = av2; av2 = avn;
    }
}

// ---------------- Fallback: fused kernel (small ws) ----------------
__global__ __launch_bounds__(256) void agru_fused_kernel(
    const float* __restrict__ x, const float* __restrict__ att,
    const float* __restrict__ h0,
    const float* __restrict__ w_ir, const float* __restrict__ w_hr,
    const float* __restrict__ b_ir, const float* __restrict__ b_hr,
    const float* __restrict__ w_ih, const float* __restrict__ w_hh,
    const float* __restrict__ b_ih, const float* __restrict__ b_hh,
    float* __restrict__ out)
{
    __shared__ float lds[4 * UDIM * UDIM];
    const int tid = threadIdx.x;
    #pragma unroll
    for (int i = 0; i < 16; ++i) {
        int e = tid + 256 * i;
        lds[e] = w_ir[e]; lds[4096 + e] = w_ih[e];
        lds[8192 + e] = w_hr[e]; lds[12288 + e] = w_hh[e];
    }
    __syncthreads();

    const int wave = tid >> 6;
    const int u = tid & 63;
    const int r0 = blockIdx.x * 8 + wave * 2;
    const int r1 = r0 + 1;

    float h_0 = h0[r0 * UDIM + u];
    float h_1 = h0[r1 * UDIM + u];
    const float bR = b_ir[u] + b_hr[u];
    const float bH = b_ih[u];
    const float bG = b_hh[u];

    const float* xp0 = x + (long)r0 * T_STEPS * UDIM + u;
    const float* xp1 = x + (long)r1 * T_STEPS * UDIM + u;
    const float* ap0 = att + (long)r0 * T_STEPS;
    const float* ap1 = att + (long)r1 * T_STEPS;
    float* op0 = out + (long)r0 * T_STEPS * UDIM + u;
    float* op1 = out + (long)r1 * T_STEPS * UDIM + u;

    float xv0 = xp0[0], xv1 = xp1[0], a0 = ap0[0], a1 = ap1[0];

    for (int t = 0; t < T_STEPS; ++t) {
        const int tn = (t + 1 < T_STEPS) ? (t + 1) : t;
        float nxv0 = xp0[(long)tn * UDIM], nxv1 = xp1[(long)tn * UDIM];
        float na0 = ap0[tn], na1 = ap1[tn];

        float accR0 = bR, accR1 = bR, accH0 = bH, accH1 = bH, accG0 = bG, accG1 = bG;
        #pragma unroll
        for (int j = 0; j < 64; ++j) {
            const float wir = lds[j * 64 + u];
            const float wih = lds[4096 + j * 64 + u];
            const float whr = lds[8192 + j * 64 + u];
            const float whh = lds[12288 + j * 64 + u];
            const float xj0 = lane_bcast(xv0, j);
            const float xj1 = lane_bcast(xv1, j);
            const float hj0 = lane_bcast(h_0, j);
            const float hj1 = lane_bcast(h_1, j);
            accR0 = fmaf(xj0, wir, accR0); accR0 = fmaf(hj0, whr, accR0);
            accH0 = fmaf(xj0, wih, accH0); accG0 = fmaf(hj0, whh, accG0);
            accR1 = fmaf(xj1, wir, accR1); accR1 = fmaf(hj1, whr, accR1);
            accH1 = fmaf(xj1, wih, accH1); accG1 = fmaf(hj1, whh, accG1);
        }
        const float r0g = fast_sigmoid(accR0);
        const float r1g = fast_sigmoid(accR1);
        const float hc0 = fast_tanh(fmaf(r0g, accG0, accH0));
        const float hc1 = fast_tanh(fmaf(r1g, accG1, accH1));
        h_0 = fmaf(a0, hc0 - h_0, h_0);
        h_1 = fmaf(a1, hc1 - h_1, h_1);
        op0[(long)t * UDIM] = h_0;
        op1[(long)t * UDIM] = h_1;
        xv0 = nxv0; xv1 = nxv1; a0 = na0; a1 = na1;
    }
}

extern "C" void kernel_launch(void* const* d_in, const int* in_sizes, int n_in,
                              void* d_out, int out_size, void* d_ws, size_t ws_size,
                              hipStream_t stream) {
    (void)in_sizes; (void)n_in; (void)out_size;

    const float* x    = (const float*)d_in[0];
    const float* att  = (const float*)d_in[1];
    const float* h0   = (const float*)d_in[2];
    const float* w_ir = (const float*)d_in[3];
    const float* w_hr = (const float*)d_in[4];
    const float* b_ir = (const float*)d_in[5];
    const float* b_hr = (const float*)d_in[6];
    const float* w_ih = (const float*)d_in[7];
    const float* w_hh = (const float*)d_in[8];
    const float* b_ih = (const float*)d_in[9];
    const float* b_hh = (const float*)d_in[10];
    float* out = (float*)d_out;

    const size_t pre_bytes = (size_t)BATCH * T_STEPS * UDIM * sizeof(float2); // 210 MB

    if (ws_size >= pre_bytes) {
        float2* pre = (float2*)d_ws;
        proj_kernel<<<dim3(1024), dim3(256), 0, stream>>>(
            x, w_ir, w_ih, b_ir, b_hr, b_ih, pre);
        rec_kernel<<<dim3(512), dim3(256), 0, stream>>>(
            pre, att, h0, w_hr, w_hh, b_hh, out);
    } else {
        agru_fused_kernel<<<dim3(256), dim3(256), 0, stream>>>(
            x, att, h0, w_ir, w_hr, b_ir, b_hr, w_ih, w_hh, b_ih, b_hh, out);
    }
}